// Round 12
// baseline (126.534 us; speedup 1.0000x reference)
//
#include <hip/hip_runtime.h>
#include <stdint.h>

// Croston's method: B=8192 series x T=2048 steps. out = Z'/V' per step.
//
// Round 23 = R21 (plain stores -- R22's NT stores were a 2x regression,
// 72us/1.4TB/s, refuted) + ONE lever: make the series prefetch REAL.
// R22's profile showed VGPR_Count=72: buf[2][8] (64 regs) + xv (32) +
// scan state cannot coexist in 72 regs, so the scheduler sank the
// prefetch loads to their use -- the R21 pipeline never existed in the
// emitted code; each wave ran load(wait) -> scan -> store serialized,
// matching the measured ~34us and the 33% read duty cycle behind the
// 15.5/24.6 GB/s-per-CU shortfall.
// Fix: depth-2 series prefetch (prologue loads S0+S1; iter i consumes
// S_i into LDS then refills the SAME buffer with S_{i+2}) and a
// __builtin_amdgcn_sched_barrier(0) hard fence right after each
// load-issue block so the scheduler cannot sink the loads. Steady state
// keeps 16-24KB vmem/wave outstanding; compiler's counted vmcnt
// (8/16/24 by in-order audit) never drains the queue. VGPR should rise
// to ~120-135 -- that rise is the diagnostic that the pipeline exists.
// Occupancy: LDS 32KB/block caps at 2 blocks/CU = 8 waves/CU regardless,
// so the VGPR increase is free.
// Per-series scan: R19's verified swizzled transpose (row=G>>3,
// quad=(G&7)^((G>>3)&7); every wave64 b128 phase covers 8 bank-quads per
// lane-octet) + p==az reduction; fold -> 6-round __shfl_up compose scan
// -> exclusive prefix -> replay. Exact; no warmup.

#define TLEN 2048

typedef float vf4 __attribute__((ext_vector_type(4)));

__global__ __launch_bounds__(256) void croston_kernel(
    const float* __restrict__ x,
    const float* __restrict__ alpha,
    const float* __restrict__ Z0,
    const float* __restrict__ V0,
    const float* __restrict__ q0,
    float* __restrict__ out)
{
    __shared__ __attribute__((aligned(16))) float lds[4][2048]; // 8KB/wave

    const int warp = threadIdx.x >> 6;
    const int lane = threadIdx.x & 63;
    const int wave = blockIdx.x * 4 + warp;   // 0..2047
    const int wid0 = wave * 4;                // 4 consecutive series
    float* W = lds[warp];                     // wave-private

    const float a  = alpha[0];
    const float ma = 1.0f - a;

    // R19 transpose addressing (verified):
    const int rg   = lane >> 3;                       // row-in-inst
    const int e    = (lane & 7) ^ rg;                 // write-side quad swizzle
    const int goff = rg * 32 + (e << 2);              // + j*256
    const int l7   = lane & 7;                        // read-side key
    const int lbase = lane * 32;

    // Hoist all 4 series' initial states (wave-uniform scalar loads).
    float zs[4], vs[4], qsx[4];
#pragma unroll
    for (int i = 0; i < 4; ++i) {
        zs[i]  = Z0[wid0 + i];
        vs[i]  = V0[wid0 + i];
        qsx[i] = q0[wid0 + i];
    }

    // ---- depth-2 prefetch prologue: S0 -> bufA, S1 -> bufB ----
    vf4 bufA[8], bufB[8];
#pragma unroll
    for (int j = 0; j < 8; ++j)
        bufA[j] = *(const vf4*)(x + (size_t)(wid0 + 0) * TLEN + j * 256 + lane * 4);
#pragma unroll
    for (int j = 0; j < 8; ++j)
        bufB[j] = *(const vf4*)(x + (size_t)(wid0 + 1) * TLEN + j * 256 + lane * 4);
    __builtin_amdgcn_sched_barrier(0);   // pin prologue load issue

#pragma unroll
    for (int i = 0; i < 4; ++i) {              // fully unrolled: static idx
        const int wid = wid0 + i;
        vf4* cur = (i & 1) ? bufB : bufA;

        // ---- transpose-in: consume cur (loaded 2 iters ago) ----
        // Compiler's counted vmcnt here leaves the newer loads/stores
        // outstanding (in-order audit: 8 at i=0, 16/24 steady state).
#pragma unroll
        for (int j = 0; j < 8; ++j)
            *(vf4*)(W + j * 256 + goff) = cur[j];

        // ---- refill the freed buffer with S(i+2); fence pins issue ----
        if (i < 2) {
#pragma unroll
            for (int j = 0; j < 8; ++j)
                cur[j] = *(const vf4*)(x + (size_t)(wid + 2) * TLEN + j * 256 + lane * 4);
        }
        __builtin_amdgcn_sched_barrier(0);  // loads may NOT sink past here

        vf4 xv[8];
#pragma unroll
        for (int m = 0; m < 8; ++m)
            xv[m] = *(const vf4*)(W + lbase + ((m ^ l7) << 2));

        // ---- fold: compose 32 per-step affine maps (p == az) ----
        float az = 1.f, bz = 0.f, r = 0.f, s = 0.f, f = 1.f, g = 0.f;
#pragma unroll
        for (int m = 0; m < 8; ++m) {
#pragma unroll
            for (int k = 0; k < 4; ++k) {
                const float xt = xv[m][k];
                const bool  nz = (xt != 0.f);
                const float az_n = ma * az;
                const float bz_n = fmaf(ma, bz, a * xt);
                const float r_n  = fmaf(ma, r, a * f);
                const float s_n  = fmaf(ma, s, a * g);
                az = nz ? az_n : az;
                bz = nz ? bz_n : bz;
                r  = nz ? r_n  : r;
                s  = nz ? s_n  : s;
                g  = nz ? 1.f  : (g + 1.f);   // r_n,s_n already took old f,g
                f  = nz ? 0.f  : f;
            }
        }

        // ---- inclusive Hillis-Steele compose scan across 64 lanes ----
#pragma unroll
        for (int d = 1; d < 64; d <<= 1) {
            const float az_o = __shfl_up(az, d);
            const float bz_o = __shfl_up(bz, d);
            const float r_o  = __shfl_up(r,  d);
            const float s_o  = __shfl_up(s,  d);
            const float f_o  = __shfl_up(f,  d);
            const float g_o  = __shfl_up(g,  d);
            if (lane >= d) {
                bz = fmaf(az, bz_o, bz);
                s  = fmaf(az, s_o, fmaf(r, g_o, s));
                r  = fmaf(az, r_o, r * f_o);
                az = az * az_o;
                g  = fmaf(f, g_o, g);
                f  = f * f_o;
            }
        }

        // ---- exclusive prefix (shift one lane; identity at lane 0) ----
        float azE = __shfl_up(az, 1), bzE = __shfl_up(bz, 1);
        float rE  = __shfl_up(r, 1),  sE  = __shfl_up(s, 1);
        float fE  = __shfl_up(f, 1),  gE  = __shfl_up(g, 1);
        if (lane == 0) {
            azE = 1.f; bzE = 0.f; rE = 0.f; sE = 0.f; fE = 1.f; gE = 0.f;
        }

        // ---- state at this lane's window start (exact) ----
        float Z = fmaf(azE, zs[i], bzE);
        float V = fmaf(azE, vs[i], fmaf(rE, qsx[i], sE));
        float q = fmaf(fE, qsx[i], gE);

        // ---- replay 32 steps, emit out = Z'/V' ----
#pragma unroll
        for (int m = 0; m < 8; ++m) {
#pragma unroll
            for (int k = 0; k < 4; ++k) {
                const float xt = xv[m][k];
                const bool  nz = (xt != 0.f);
                const float Zn = fmaf(ma, Z, a * xt);
                const float Vn = fmaf(ma, V, a * q);
                Z = nz ? Zn : Z;
                V = nz ? Vn : V;
                q = nz ? 1.f : (q + 1.f);
                xv[m][k] = Z * __builtin_amdgcn_rcpf(V);
            }
        }

        // ---- transpose-out -> coalesced PLAIN stores (drain under next scan) ----
#pragma unroll
        for (int m = 0; m < 8; ++m)
            *(vf4*)(W + lbase + ((m ^ l7) << 2)) = xv[m];
#pragma unroll
        for (int j = 0; j < 8; ++j) {
            const vf4 o = *(const vf4*)(W + j * 256 + goff);
            *(vf4*)(out + (size_t)wid * TLEN + j * 256 + lane * 4) = o;
        }
    }
}

extern "C" void kernel_launch(void* const* d_in, const int* in_sizes, int n_in,
                              void* d_out, int out_size, void* d_ws, size_t ws_size,
                              hipStream_t stream) {
    const float* x     = (const float*)d_in[0];
    const float* alpha = (const float*)d_in[1];
    const float* Z0    = (const float*)d_in[2];
    const float* V0    = (const float*)d_in[3];
    const float* q0    = (const float*)d_in[4];
    float* out = (float*)d_out;

    // 2048 waves x 4 consecutive series each; 512 blocks = 2 blocks/CU
    // (32KB LDS each), 8 waves/CU, depth-2 pinned series prefetch.
    dim3 block(256);
    dim3 grid(512);
    croston_kernel<<<grid, block, 0, stream>>>(x, alpha, Z0, V0, q0, out);
}

// Round 13
// 118.838 us; speedup vs baseline: 1.0648x; 1.0648x over previous
//
#include <hip/hip_runtime.h>
#include <stdint.h>

// Croston's method: B=8192 series x T=2048 steps. out = Z'/V' per step.
//
// Round 24 = R21 (plain stores, no fences -- R23's sched_barrier(0) was a
// -7us regression: it blocks ALL reordering, not just load-sinking) + ONE
// new lever: per-wave TEMPORAL STAGGER to break wave lockstep.
// Model fitting R19-R23: per-CU totals HBM ~16us + DS ~10us + VALU ~6us;
// measured 31-34us == the SERIAL sum in every variant; perfect overlap
// would be ~16us. m13's copy (3.15+3.15 TB/s concurrent read+write)
// proves the memory system handles the mix -- so the pipes aren't
// overlapping ACROSS waves. Cause: all waves launch together, run
// identical code with identical timing -> every wave is in the same
// phase (load burst / DS+VALU scan / store burst) at the same wall-clock
// time, forever. Memory idles during scans; DS idles during loads. More
// waves (R20) just enlarges the synchronized bursts; intra-wave
// pipelining (R21: compiler-defeated per VGPR=72; R23: fence-poisoned)
// never touched cross-wave phase alignment.
// Fix: wave w sleeps sid*~700 cycles before its first load, sid in 0..7
// distinct for co-resident waves (warp + block-bit parity hash covering
// both plausible block->CU mappings). Series-round period ~4000-6000 cyc
// -> 8 waves spread across a full period -> pipes run concurrently.
// Cost <= 2us once. Everything else R21 verbatim.
// Per-series scan: R19's verified swizzled transpose (row=G>>3,
// quad=(G&7)^((G>>3)&7)), fold (p==az) -> 6-round __shfl_up compose scan
// -> exclusive prefix -> replay. Exact; no warmup.

#define TLEN 2048

typedef float vf4 __attribute__((ext_vector_type(4)));

__global__ __launch_bounds__(256) void croston_kernel(
    const float* __restrict__ x,
    const float* __restrict__ alpha,
    const float* __restrict__ Z0,
    const float* __restrict__ V0,
    const float* __restrict__ q0,
    float* __restrict__ out)
{
    __shared__ __attribute__((aligned(16))) float lds[4][2048]; // 8KB/wave

    const int warp = threadIdx.x >> 6;
    const int lane = threadIdx.x & 63;
    const int wave = blockIdx.x * 4 + warp;   // 0..2047
    const int wid0 = wave * 4;                // 4 consecutive series
    float* W = lds[warp];                     // wave-private

    const float a  = alpha[0];
    const float ma = 1.0f - a;

    // ---- phase stagger: sid distinct for co-resident waves ----
    // parity hash over block bits 3..8 covers both adjacent-pair and
    // stride-256-pair block->CU mappings (either way, co-resident blocks
    // differ in at least one hashed bit with high probability).
    const int bid = blockIdx.x;
    const int par = ((bid >> 3) ^ (bid >> 4) ^ (bid >> 5) ^
                     (bid >> 6) ^ (bid >> 7) ^ (bid >> 8)) & 1;
    const int sid = warp + (par << 2);        // 0..7
    #pragma unroll 1
    for (int t = 0; t < sid; ++t)
        __builtin_amdgcn_s_sleep(11);         // ~704 cyc each

    // R19 transpose addressing (verified):
    const int rg   = lane >> 3;                       // row-in-inst
    const int e    = (lane & 7) ^ rg;                 // write-side quad swizzle
    const int goff = rg * 32 + (e << 2);              // + j*256
    const int l7   = lane & 7;                        // read-side key
    const int lbase = lane * 32;

    // Hoist all 4 series' initial states (wave-uniform scalar loads).
    float zs[4], vs[4], qsx[4];
#pragma unroll
    for (int i = 0; i < 4; ++i) {
        zs[i]  = Z0[wid0 + i];
        vs[i]  = V0[wid0 + i];
        qsx[i] = q0[wid0 + i];
    }

    vf4 buf[2][8];                             // double-buffered raw loads
#pragma unroll
    for (int j = 0; j < 8; ++j)
        buf[0][j] = *(const vf4*)(x + (size_t)wid0 * TLEN + j * 256 + lane * 4);

#pragma unroll
    for (int i = 0; i < 4; ++i) {              // fully unrolled: static idx
        const int wid = wid0 + i;

        // ---- prefetch next series (flies under this series' scan) ----
        if (i < 3) {
#pragma unroll
            for (int j = 0; j < 8; ++j)
                buf[(i + 1) & 1][j] =
                    *(const vf4*)(x + (size_t)(wid + 1) * TLEN + j * 256 + lane * 4);
        }

        // ---- transpose-in (waits only this series' loads) ----
#pragma unroll
        for (int j = 0; j < 8; ++j)
            *(vf4*)(W + j * 256 + goff) = buf[i & 1][j];
        vf4 xv[8];
#pragma unroll
        for (int m = 0; m < 8; ++m)
            xv[m] = *(const vf4*)(W + lbase + ((m ^ l7) << 2));

        // ---- fold: compose 32 per-step affine maps (p == az) ----
        float az = 1.f, bz = 0.f, r = 0.f, s = 0.f, f = 1.f, g = 0.f;
#pragma unroll
        for (int m = 0; m < 8; ++m) {
#pragma unroll
            for (int k = 0; k < 4; ++k) {
                const float xt = xv[m][k];
                const bool  nz = (xt != 0.f);
                const float az_n = ma * az;
                const float bz_n = fmaf(ma, bz, a * xt);
                const float r_n  = fmaf(ma, r, a * f);
                const float s_n  = fmaf(ma, s, a * g);
                az = nz ? az_n : az;
                bz = nz ? bz_n : bz;
                r  = nz ? r_n  : r;
                s  = nz ? s_n  : s;
                g  = nz ? 1.f  : (g + 1.f);   // r_n,s_n already took old f,g
                f  = nz ? 0.f  : f;
            }
        }

        // ---- inclusive Hillis-Steele compose scan across 64 lanes ----
#pragma unroll
        for (int d = 1; d < 64; d <<= 1) {
            const float az_o = __shfl_up(az, d);
            const float bz_o = __shfl_up(bz, d);
            const float r_o  = __shfl_up(r,  d);
            const float s_o  = __shfl_up(s,  d);
            const float f_o  = __shfl_up(f,  d);
            const float g_o  = __shfl_up(g,  d);
            if (lane >= d) {
                bz = fmaf(az, bz_o, bz);
                s  = fmaf(az, s_o, fmaf(r, g_o, s));
                r  = fmaf(az, r_o, r * f_o);
                az = az * az_o;
                g  = fmaf(f, g_o, g);
                f  = f * f_o;
            }
        }

        // ---- exclusive prefix (shift one lane; identity at lane 0) ----
        float azE = __shfl_up(az, 1), bzE = __shfl_up(bz, 1);
        float rE  = __shfl_up(r, 1),  sE  = __shfl_up(s, 1);
        float fE  = __shfl_up(f, 1),  gE  = __shfl_up(g, 1);
        if (lane == 0) {
            azE = 1.f; bzE = 0.f; rE = 0.f; sE = 0.f; fE = 1.f; gE = 0.f;
        }

        // ---- state at this lane's window start (exact) ----
        float Z = fmaf(azE, zs[i], bzE);
        float V = fmaf(azE, vs[i], fmaf(rE, qsx[i], sE));
        float q = fmaf(fE, qsx[i], gE);

        // ---- replay 32 steps, emit out = Z'/V' ----
#pragma unroll
        for (int m = 0; m < 8; ++m) {
#pragma unroll
            for (int k = 0; k < 4; ++k) {
                const float xt = xv[m][k];
                const bool  nz = (xt != 0.f);
                const float Zn = fmaf(ma, Z, a * xt);
                const float Vn = fmaf(ma, V, a * q);
                Z = nz ? Zn : Z;
                V = nz ? Vn : V;
                q = nz ? 1.f : (q + 1.f);
                xv[m][k] = Z * __builtin_amdgcn_rcpf(V);
            }
        }

        // ---- transpose-out -> coalesced stores (drain under next scan) ----
#pragma unroll
        for (int m = 0; m < 8; ++m)
            *(vf4*)(W + lbase + ((m ^ l7) << 2)) = xv[m];
#pragma unroll
        for (int j = 0; j < 8; ++j) {
            const vf4 o = *(const vf4*)(W + j * 256 + goff);
            *(vf4*)(out + (size_t)wid * TLEN + j * 256 + lane * 4) = o;
        }
    }
}

extern "C" void kernel_launch(void* const* d_in, const int* in_sizes, int n_in,
                              void* d_out, int out_size, void* d_ws, size_t ws_size,
                              hipStream_t stream) {
    const float* x     = (const float*)d_in[0];
    const float* alpha = (const float*)d_in[1];
    const float* Z0    = (const float*)d_in[2];
    const float* V0    = (const float*)d_in[3];
    const float* q0    = (const float*)d_in[4];
    float* out = (float*)d_out;

    // 2048 waves x 4 consecutive series each; 512 blocks = 2 blocks/CU
    // (32KB LDS each), 8 waves/CU, phase-staggered cross-series pipeline.
    dim3 block(256);
    dim3 grid(512);
    croston_kernel<<<grid, block, 0, stream>>>(x, alpha, Z0, V0, q0, out);
}